// Round 8
// baseline (287.883 us; speedup 1.0000x reference)
//
#include <hip/hip_runtime.h>
#include <math.h>

// Problem constants (match reference)
#define B_ 4
#define L_ 2048
#define H_ 16
#define D_ 64
#define M_ 128
#define TC_ 64              // chunk length
#define NC_ (L_ / TC_)      // 32 chunks
#define EPSK 1e-6f
#define DATA_SCALE 0.35355339059327379f  // 64^{-1/4}
#define RATIO 0.08838834764831845f       // 128^{-1/2}

typedef __bf16 bf16;
typedef bf16 bf16x4 __attribute__((ext_vector_type(4)));
typedef bf16 bf16x8 __attribute__((ext_vector_type(8)));
typedef float floatx4 __attribute__((ext_vector_type(4)));

#define PK64 72     // padded [row][tau] stride (bf16): 144 B rows, 16B-aligned
#define FS_ 136     // feat-tile stride: 272 B rows, 16B-aligned

__device__ __forceinline__ unsigned pk(bf16 a, bf16 b) {
    return (unsigned)__builtin_bit_cast(unsigned short, a) |
           ((unsigned)__builtin_bit_cast(unsigned short, b) << 16);
}

// ---- order-preserving float<->uint for atomic max ----
__device__ __forceinline__ unsigned enc_f(float f) {
    unsigned u = __float_as_uint(f);
    return (u & 0x80000000u) ? ~u : (u | 0x80000000u);
}
__device__ __forceinline__ float dec_f(unsigned u) {
    unsigned b = (u & 0x80000000u) ? (u ^ 0x80000000u) : ~u;
    return __uint_as_float(b);
}

// ---------------------------------------------------------------------------
// One-time: split proj into hi/lo bf16 in MFMA B-fragment order.
// pf[(tc*2 + k0h)*64 + lane][e] = proj[16*tc + (lane&15)][k0h*32 + (lane>>4)*8 + e]
// 16 KB each -> L2-resident for all feat blocks. Also zeroes mx.
// ---------------------------------------------------------------------------
__global__ __launch_bounds__(256) void proj_split(const float* __restrict__ proj,
                                                  bf16* __restrict__ pfh,
                                                  bf16* __restrict__ pfl,
                                                  unsigned* __restrict__ mx) {
    int f = blockIdx.x * 256 + threadIdx.x;   // 0..1023 fragments
    if (blockIdx.x == 0 && threadIdx.x < B_ * H_) mx[threadIdx.x] = 0u;
    int tc = f >> 7, k0h = (f >> 6) & 1, lane = f & 63;
    int lr = lane & 15, quad = lane >> 4;
    const float* src = proj + (16 * tc + lr) * 64 + k0h * 32 + quad * 8;
    float4 x0 = *(const float4*)src;
    float4 x1 = *(const float4*)(src + 4);
    float a[8] = {x0.x, x0.y, x0.z, x0.w, x1.x, x1.y, x1.z, x1.w};
    bf16x8 hi, lo;
#pragma unroll
    for (int e = 0; e < 8; e++) {
        bf16 h = (bf16)a[e];
        hi[e] = h;
        lo[e] = (bf16)(a[e] - (float)h);
    }
    *(bf16x8*)(pfh + (size_t)f * 8) = hi;
    *(bf16x8*)(pfl + (size_t)f * 8) = lo;
}

// ---------------------------------------------------------------------------
// k max pass, WAVE-PER-BLOCK (8192 x 64thr): dd via hi-only MFMA, per-wave
// atomicMax. No LDS, no barrier.
// ---------------------------------------------------------------------------
__global__ __launch_bounds__(64, 4) void feat_max(const float* __restrict__ k,
                                                  const bf16* __restrict__ pfh,
                                                  unsigned* __restrict__ mxk) {
    int blk = blockIdx.x;
    int w = blk & 3, c = (blk >> 2) & 31, h = (blk >> 7) & 15, b = blk >> 11;
    int l0 = c * 64;
    int lane = threadIdx.x, lr = lane & 15, quad = lane >> 4;

    const float* drow = k +
        ((size_t)(b * L_ + l0 + 16 * w + lr) * H_ + h) * D_ + quad * 8;
    bf16x8 ah[2];
#pragma unroll
    for (int k0 = 0; k0 < 2; k0++) {
        float4 x0 = *(const float4*)(drow + k0 * 32);
        float4 x1 = *(const float4*)(drow + k0 * 32 + 4);
        float a[8] = {x0.x, x0.y, x0.z, x0.w, x1.x, x1.y, x1.z, x1.w};
#pragma unroll
        for (int e = 0; e < 8; e++) ah[k0][e] = (bf16)(DATA_SCALE * a[e]);
    }

    floatx4 acc[8];
#pragma unroll
    for (int tc = 0; tc < 8; tc++) acc[tc] = (floatx4){0.f, 0.f, 0.f, 0.f};
    const bf16x8* ph = (const bf16x8*)pfh + lane;
#pragma unroll
    for (int tc = 0; tc < 8; tc++)
#pragma unroll
        for (int k0 = 0; k0 < 2; k0++) {
            bf16x8 bh = ph[(tc * 2 + k0) * 64];
            acc[tc] = __builtin_amdgcn_mfma_f32_16x16x32_bf16(ah[k0], bh, acc[tc], 0, 0, 0);
        }

    float mm = acc[0][0];
#pragma unroll
    for (int tc = 0; tc < 8; tc++)
#pragma unroll
        for (int reg = 0; reg < 4; reg++) mm = fmaxf(mm, acc[tc][reg]);
#pragma unroll
    for (int off = 1; off < 64; off <<= 1) mm = fmaxf(mm, __shfl_xor(mm, off, 64));
    if (lane == 0) atomicMax(&mxk[b * H_ + h], enc_f(mm));
}

// ---------------------------------------------------------------------------
// k exp pass, WAVE-PER-BLOCK (8192 x 64thr) -> kp in FRAGMENT order per tile:
// frag f = ki*4+tc: lane,e -> (tau = 16tc + (lane&15), m = 32ki + (lane>>4)*8+e).
// This wave produces frags with tc == w. LDS 16 rows, wave-local, no barrier.
// ---------------------------------------------------------------------------
__global__ __launch_bounds__(64, 4) void feat_k(const float* __restrict__ kin,
                                                const bf16* __restrict__ pfh,
                                                const bf16* __restrict__ pfl,
                                                const unsigned* __restrict__ mxk,
                                                bf16* __restrict__ kp) {
    __shared__ __align__(16) bf16 sc[16 * FS_];
    int blk = blockIdx.x;
    int w = blk & 3, c = (blk >> 2) & 31, h = (blk >> 7) & 15, b = blk >> 11;
    int l0 = c * 64;
    int lane = threadIdx.x, lr = lane & 15, quad = lane >> 4;
    int tile = (blk >> 2);               // (b,h,c) tile index = blk/4

    const float* drow = kin +
        ((size_t)(b * L_ + l0 + 16 * w + lr) * H_ + h) * D_ + quad * 8;
    bf16x8 ah[2], al[2];
    float ss = 0.f;
#pragma unroll
    for (int k0 = 0; k0 < 2; k0++) {
        float4 x0 = *(const float4*)(drow + k0 * 32);
        float4 x1 = *(const float4*)(drow + k0 * 32 + 4);
        float a[8] = {x0.x, x0.y, x0.z, x0.w, x1.x, x1.y, x1.z, x1.w};
#pragma unroll
        for (int e = 0; e < 8; e++) {
            float s = DATA_SCALE * a[e];
            ss += s * s;
            bf16 hh = (bf16)s;
            ah[k0][e] = hh;
            al[k0][e] = (bf16)(s - (float)hh);
        }
    }
    ss += __shfl_xor(ss, 16, 64);
    ss += __shfl_xor(ss, 32, 64);
    float ssrow = 0.5f * ss;

    floatx4 acc[8];
#pragma unroll
    for (int tc = 0; tc < 8; tc++) acc[tc] = (floatx4){0.f, 0.f, 0.f, 0.f};
    const bf16x8* ph = (const bf16x8*)pfh + lane;
    const bf16x8* pl = (const bf16x8*)pfl + lane;
#pragma unroll
    for (int tc = 0; tc < 8; tc++)
#pragma unroll
        for (int k0 = 0; k0 < 2; k0++) {
            bf16x8 bh = ph[(tc * 2 + k0) * 64];
            bf16x8 bl = pl[(tc * 2 + k0) * 64];
            acc[tc] = __builtin_amdgcn_mfma_f32_16x16x32_bf16(ah[k0], bh, acc[tc], 0, 0, 0);
            acc[tc] = __builtin_amdgcn_mfma_f32_16x16x32_bf16(al[k0], bh, acc[tc], 0, 0, 0);
            acc[tc] = __builtin_amdgcn_mfma_f32_16x16x32_bf16(ah[k0], bl, acc[tc], 0, 0, 0);
        }

    float mxg = dec_f(mxk[b * H_ + h]);
#pragma unroll
    for (int reg = 0; reg < 4; reg++) {
        float dg = __shfl(ssrow, 4 * quad + reg, 64);
        float sh = dg + mxg;
#pragma unroll
        for (int tc = 0; tc < 8; tc++) {
            float val = RATIO * (__expf(acc[tc][reg] - sh) + EPSK);
            sc[(4 * quad + reg) * FS_ + 16 * tc + lr] = (bf16)val;
        }
    }

    // frag store: frags (ki*4 + w), straight uint4 LDS->global
    {
        uint4* kout = (uint4*)(kp + (size_t)tile * 8192);
#pragma unroll
        for (int ki = 0; ki < 4; ki++)
            kout[(ki * 4 + w) * 64 + lane] =
                *(const uint4*)(sc + lr * FS_ + 32 * ki + 8 * quad);
    }
}

// ---------------------------------------------------------------------------
// Chunk sums + V transpose fused. Reads kp (fragment order) and v (fp32),
// builds kT[m][tau] / vT[d][tau] in LDS (lane=tau scalar writes: bank-safe);
// computes S^T[d][m] (stored in fragment order), ds[m]; writes vbT for attn.
// ---------------------------------------------------------------------------
__global__ __launch_bounds__(256) void chunk_v(const bf16* __restrict__ kp,
                                               const float* __restrict__ v,
                                               bf16* __restrict__ S,
                                               float* __restrict__ ds,
                                               bf16* __restrict__ vbT) {
    __shared__ __align__(16) bf16 kT[128 * PK64];   // [m][tau] padded
    __shared__ __align__(16) bf16 vT[64 * PK64];    // [d][tau] padded
    int tid = threadIdx.x;
    int blk = blockIdx.x;
    int c = blk & 31, bh = blk >> 5;
    int h = bh & 15, b = bh >> 4;
    int l0 = c * 64;
    int w = tid >> 6, lane = tid & 63, lr = lane & 15, quad = lane >> 4;

    // kp tile (fragment order) -> kT[m][tau]; lane = tau
    const bf16* kpt = kp + (size_t)blk * 8192;
#pragma unroll
    for (int i = 0; i < 4; i++) {
        int m8 = w * 4 + i;              // 0..15
        bf16x8 kv = *(const bf16x8*)(kpt +
            (((m8 >> 2) * 4 + (lane >> 4)) * 64 + (m8 & 3) * 16 + (lane & 15)) * 8);
#pragma unroll
        for (int e = 0; e < 8; e++) kT[(m8 * 8 + e) * PK64 + lane] = kv[e];
    }
    // v rows (fp32) -> vT[d][tau] bf16; lane = tau
    {
        const float* vrow = v + ((size_t)(b * L_ + l0 + lane) * H_ + h) * D_;
#pragma unroll
        for (int i = 0; i < 4; i++) {
            int d4 = w * 4 + i;          // 0..15
            float4 x = *(const float4*)(vrow + d4 * 4);
            vT[(d4 * 4 + 0) * PK64 + lane] = (bf16)x.x;
            vT[(d4 * 4 + 1) * PK64 + lane] = (bf16)x.y;
            vT[(d4 * 4 + 2) * PK64 + lane] = (bf16)x.z;
            vT[(d4 * 4 + 3) * PK64 + lane] = (bf16)x.w;
        }
    }
    __syncthreads();

    floatx4 acc[8];
#pragma unroll
    for (int tc = 0; tc < 8; tc++) acc[tc] = (floatx4){0.f, 0.f, 0.f, 0.f};
#pragma unroll
    for (int k0 = 0; k0 < 64; k0 += 32) {
        bf16x8 a = *(const bf16x8*)(vT + (16 * w + lr) * PK64 + k0 + quad * 8);
#pragma unroll
        for (int tc = 0; tc < 8; tc++) {
            bf16x8 bb = *(const bf16x8*)(kT + (16 * tc + lr) * PK64 + k0 + quad * 8);
            acc[tc] = __builtin_amdgcn_mfma_f32_16x16x32_bf16(a, bb, acc[tc], 0, 0, 0);
        }
    }

    // vbT [bh][d][L] from vT (pairs contiguous in the transposed tile)
    {
        size_t ob = (size_t)(bh * D_) * (size_t)L_ + l0;
#pragma unroll
        for (int i = 0; i < 8; i++) {
            int e2 = tid + 256 * i;      // 2048 pairs
            int d = e2 >> 5, tau2 = (e2 & 31) * 2;
            *(unsigned*)(vbT + ob + (size_t)d * L_ + tau2) =
                *(const unsigned*)(vT + d * PK64 + tau2);
        }
    }

    // ds[m]: 2 threads per m, 32 taus each (reads kT before repack overwrites)
    float dsv = 0.f;
    {
        int m = tid >> 1, half = tid & 1;
        const bf16x8* kr = (const bf16x8*)(kT + m * PK64 + half * 32);
#pragma unroll
        for (int j = 0; j < 4; j++) {
            bf16x8 vv = kr[j];
#pragma unroll
            for (int e = 0; e < 8; e++) dsv += (float)vv[e];
        }
        dsv += __shfl_xor(dsv, 1, 64);
    }
    __syncthreads();

    // repack acc into kT area in FRAGMENT order (value (d,m) at
    // ((ki*4+tcf)*64 + quadf*16 + lrf)*8 + e), then coalesced flat store
    bf16* scr = kT;
#pragma unroll
    for (int tc = 0; tc < 8; tc++)
#pragma unroll
        for (int reg = 0; reg < 4; reg++)
            scr[((tc >> 1) * 4 + w) * 512 +
                (((((tc & 1) << 1) | (lr >> 3)) * 16) + 4 * quad + reg) * 8 +
                (lr & 7)] = (bf16)acc[tc][reg];
    if ((tid & 1) == 0) ds[(size_t)blk * M_ + (tid >> 1)] = dsv;
    __syncthreads();
#pragma unroll
    for (int i = 0; i < 4; i++) {
        int e = tid + 256 * i;           // 1024 uint4
        ((uint4*)S)[(size_t)blk * 1024 + e] = ((const uint4*)scr)[e];
    }
}

// Exclusive prefix over chunks, bf16 in place (fp32 carries), loads
// prefetched to registers. Positional scan -> layout-agnostic (frag order ok).
// seg==0 blocks also scan ds.
__global__ void prefix_SD(unsigned* __restrict__ S, float* __restrict__ ds) {
    int blk = blockIdx.x;
    int seg = blk & 15, bh = blk >> 4;
    int p = seg * 256 + threadIdx.x;            // 0..4095 uint pairs per chunk
    size_t base = (size_t)bh * NC_ * 4096 + p;
    unsigned uv[NC_];
#pragma unroll
    for (int c = 0; c < NC_; c++) uv[c] = S[base + (size_t)c * 4096];
    float c0 = 0.f, c1 = 0.f;
#pragma unroll
    for (int c = 0; c < NC_; c++) {
        unsigned u = uv[c];
        float f0 = (float)__builtin_bit_cast(bf16, (unsigned short)(u & 0xffffu));
        float f1 = (float)__builtin_bit_cast(bf16, (unsigned short)(u >> 16));
        S[base + (size_t)c * 4096] = pk((bf16)c0, (bf16)c1);
        c0 += f0; c1 += f1;
    }
    if (seg == 0 && threadIdx.x < 128) {
        int m = threadIdx.x;
        size_t dbase = (size_t)bh * NC_ * M_ + m;
        float dv[NC_];
#pragma unroll
        for (int c = 0; c < NC_; c++) dv[c] = ds[dbase + (size_t)c * M_];
        float carry = 0.f;
#pragma unroll
        for (int c = 0; c < NC_; c++) {
            ds[dbase + (size_t)c * M_] = carry;
            carry += dv[c];
        }
    }
}

// ---------------------------------------------------------------------------
// Fused q-feature-map + attention, WAVE-PER-BLOCK (8192 x 64thr).
// Block = (bh, c, w): this wave owns t-rows l0+16w..l0+16w+15. All LDS (16
// fsc rows) is private to the wave -> no barrier. w in the LOW blockIdx bits
// so the 4 w-blocks of a chunk co-schedule and share Sp/kp tiles in L2.
// __launch_bounds__(64,4) -> VGPR cap 128: 16 frag loads can stay in flight
// (round-7's 256-thr/(256,4) capped VGPR at 64 and serialized them).
// kp frags: only tc<=w loaded (wave-uniform guard) -> -37.5% kp fetch.
// ---------------------------------------------------------------------------
__global__ __launch_bounds__(64, 4) void attn_q(const float* __restrict__ q,
                                                const bf16* __restrict__ pfh,
                                                const bf16* __restrict__ pfl,
                                                const bf16* __restrict__ kp,
                                                const bf16* __restrict__ vbT,
                                                const bf16* __restrict__ Sp,
                                                const float* __restrict__ dp,
                                                float* __restrict__ out) {
    __shared__ __align__(16) bf16 fsc[16 * FS_];   // wave-own rows; scores cols 0..63

    int blk = blockIdx.x;
    int w = blk & 3, c = (blk >> 2) & 31, bh = blk >> 7;
    int h = bh & 15, b = bh >> 4;
    int l0 = c * 64;
    int tile = blk >> 2;                 // (bh,c) tile index
    int lane = threadIdx.x, lr = lane & 15, quad = lane >> 4;

    // ---- feature map for this wave's 16 q rows ----
    const float* drow = q +
        ((size_t)(b * L_ + l0 + 16 * w + lr) * H_ + h) * D_ + quad * 8;
    bf16x8 ah[2], al[2];
    float ss = 0.f;
#pragma unroll
    for (int k0 = 0; k0 < 2; k0++) {
        float4 x0 = *(const float4*)(drow + k0 * 32);
        float4 x1 = *(const float4*)(drow + k0 * 32 + 4);
        float a[8] = {x0.x, x0.y, x0.z, x0.w, x1.x, x1.y, x1.z, x1.w};
#pragma unroll
        for (int e = 0; e < 8; e++) {
            float s = DATA_SCALE * a[e];
            ss += s * s;
            bf16 hh = (bf16)s;
            ah[k0][e] = hh;
            al[k0][e] = (bf16)(s - (float)hh);
        }
    }
    ss += __shfl_xor(ss, 16, 64);
    ss += __shfl_xor(ss, 32, 64);
    float ssrow = 0.5f * ss;

    floatx4 facc[8];
#pragma unroll
    for (int tc = 0; tc < 8; tc++) facc[tc] = (floatx4){0.f, 0.f, 0.f, 0.f};
    {
        const bf16x8* ph = (const bf16x8*)pfh + lane;
        const bf16x8* pl = (const bf16x8*)pfl + lane;
#pragma unroll
        for (int tc = 0; tc < 8; tc++)
#pragma unroll
            for (int k0 = 0; k0 < 2; k0++) {
                bf16x8 bh = ph[(tc * 2 + k0) * 64];
                bf16x8 bl = pl[(tc * 2 + k0) * 64];
                facc[tc] = __builtin_amdgcn_mfma_f32_16x16x32_bf16(ah[k0], bh, facc[tc], 0, 0, 0);
                facc[tc] = __builtin_amdgcn_mfma_f32_16x16x32_bf16(al[k0], bh, facc[tc], 0, 0, 0);
                facc[tc] = __builtin_amdgcn_mfma_f32_16x16x32_bf16(ah[k0], bl, facc[tc], 0, 0, 0);
            }
    }
#pragma unroll
    for (int reg = 0; reg < 4; reg++) {
        float m = facc[0][reg];
#pragma unroll
        for (int tc = 1; tc < 8; tc++) m = fmaxf(m, facc[tc][reg]);
        m = fmaxf(m, __shfl_xor(m, 1, 64));
        m = fmaxf(m, __shfl_xor(m, 2, 64));
        m = fmaxf(m, __shfl_xor(m, 4, 64));
        m = fmaxf(m, __shfl_xor(m, 8, 64));
        float dg = __shfl(ssrow, 4 * quad + reg, 64);
        float sh = dg + m;
#pragma unroll
        for (int tc = 0; tc < 8; tc++) {
            float val = RATIO * (__expf(facc[tc][reg] - sh) + EPSK);
            fsc[(4 * quad + reg) * FS_ + 16 * tc + lr] = (bf16)val;
        }
    }

    // Q A-frags from fsc (same wave wrote them; lgkmcnt ordering suffices)
    bf16x8 af[4];
#pragma unroll
    for (int k = 0; k < 4; k++)
        af[k] = *(const bf16x8*)(fsc + lr * FS_ + 32 * k + quad * 8);

    floatx4 acc[4];
#pragma unroll
    for (int tc = 0; tc < 4; tc++) acc[tc] = (floatx4){0.f, 0.f, 0.f, 0.f};

    // phase 1: Qp . S_prev (frag-order, contiguous 1KB/wave loads)
    {
        const bf16x8* spb = (const bf16x8*)(Sp + (size_t)tile * 8192) + lane;
        bf16x8 sp4[16];
#pragma unroll
        for (int f = 0; f < 16; f++) sp4[f] = spb[f * 64];
#pragma unroll
        for (int ki = 0; ki < 4; ki++)
#pragma unroll
            for (int tc = 0; tc < 4; tc++)
                acc[tc] = __builtin_amdgcn_mfma_f32_16x16x32_bf16(af[ki], sp4[ki * 4 + tc],
                                                                  acc[tc], 0, 0, 0);
    }

    // phase 2a: kp frags tc<=w only (wave-uniform guard; static reg indices)
    floatx4 acc2[4];
#pragma unroll
    for (int tc = 0; tc < 4; tc++) acc2[tc] = (floatx4){0.f, 0.f, 0.f, 0.f};
    {
        const bf16x8* kpb = (const bf16x8*)(kp + (size_t)tile * 8192) + lane;
        bf16x8 kb[16];
#pragma unroll
        for (int ki = 0; ki < 4; ki++)
#pragma unroll
            for (int tc = 0; tc < 4; tc++)
                if (tc <= w) kb[ki * 4 + tc] = kpb[(ki * 4 + tc) * 64];
#pragma unroll
        for (int ki = 0; ki < 4; ki++)
#pragma unroll
            for (int tc = 0; tc < 4; tc++)
                if (tc <= w)
                    acc2[tc] = __builtin_amdgcn_mfma_f32_16x16x32_bf16(af[ki], kb[ki * 4 + tc],
                                                                       acc2[tc], 0, 0, 0);
    }

    // mask + den partials + bf16 scores into wave-own fsc rows (cols 0..63)
    float densc[4];
    {
        float dsum[4] = {0.f, 0.f, 0.f, 0.f};
#pragma unroll
        for (int tc = 0; tc < 4; tc++) {
#pragma unroll
            for (int reg = 0; reg < 4; reg++) {
                int tg = 16 * w + 4 * quad + reg, tau = 16 * tc + lr;
                float vv = (tc <= w) ? acc2[tc][reg] : 0.f;
                if (tau > tg) vv = 0.f;
                dsum[reg] += vv;
                fsc[(4 * quad + reg) * FS_ + tau] = (bf16)vv;
            }
        }
#pragma unroll
        for (int reg = 0; reg < 4; reg++) {
            float s = dsum[reg];
            s += __shfl_xor(s, 1, 64);
            s += __shfl_xor(s, 2, 64);
            s += __shfl_xor(s, 4, 64);
            s += __shfl_xor(s, 8, 64);
            densc[reg] = s;
        }
    }

    // den0[16w+lr] = qp_row . dprev (direct from global, L1/L2-hit 512B)
    float den0v = 0.f;
    {
        const float* dpb = dp + (size_t)tile * M_ + quad * 8;
#pragma unroll
        for (int k = 0; k < 4; k++) {
            float4 d0 = *(const float4*)(dpb + 32 * k);
            float4 d1 = *(const float4*)(dpb + 32 * k + 4);
            den0v += (float)af[k][0] * d0.x + (float)af[k][1] * d0.y +
                     (float)af[k][2] * d0.z + (float)af[k][3] * d0.w +
                     (float)af[k][4] * d1.x + (float)af[k][5] * d1.y +
                     (float)af[k][6] * d1.z + (float)af[k][7] * d1.w;
        }
    }
    den0v += __shfl_xor(den0v, 16, 64);
    den0v += __shfl_xor(den0v, 32, 64);

    // phase 2b: Sc . V -- scores from wave-own fsc rows, V-frags direct from
    // global vbT (chunk-exclusive 128B segments)
    {
        const bf16* vbb = vbT + (size_t)(bh * D_) * L_ + l0 + quad * 8;
#pragma unroll
        for (int k0i = 0; k0i < 2; k0i++) {
            if (k0i == 0 || w >= 2) {
                int k0 = k0i * 32;
                bf16x8 a = *(const bf16x8*)(fsc + lr * FS_ + k0 + quad * 8);
#pragma unroll
                for (int tc = 0; tc < 4; tc++) {
                    bf16x8 bb = *(const bf16x8*)(vbb + (size_t)(16 * tc + lr) * L_ + k0);
                    acc[tc] = __builtin_amdgcn_mfma_f32_16x16x32_bf16(a, bb, acc[tc], 0, 0, 0);
                }
            }
        }
    }

    // epilogue
    {
        float inv[4];
#pragma unroll
        for (int reg = 0; reg < 4; reg++) {
            float d0 = __shfl(den0v, 4 * quad + reg, 64);  // row 16w+4q+reg
            inv[reg] = 1.0f / (d0 + densc[reg]);
        }
#pragma unroll
        for (int tc = 0; tc < 4; tc++)
#pragma unroll
            for (int reg = 0; reg < 4; reg++)
                out[((size_t)(b * L_ + l0 + 16 * w + 4 * quad + reg) * H_ + h) * D_ +
                    16 * tc + lr] = acc[tc][reg] * inv[reg];
    }
}

extern "C" void kernel_launch(void* const* d_in, const int* in_sizes, int n_in,
                              void* d_out, int out_size, void* d_ws, size_t ws_size,
                              hipStream_t stream) {
    const float* q = (const float*)d_in[0];
    const float* k = (const float*)d_in[1];
    const float* v = (const float*)d_in[2];
    const float* proj = (const float*)d_in[3];
    float* out = (float*)d_out;
    char* W = (char*)d_ws;

    // workspace layout (bytes)
    bf16* kp   = (bf16*)(W);                       //  33,554,432  frag-order tiles
    bf16* vbT  = (bf16*)(W + 33554432ull);         //  16,777,216  [bh][d][L]
    bf16* S    = (bf16*)(W + 50331648ull);         //  33,554,432  frag-order tiles
    float* ds  = (float*)(W + 83886080ull);        //   1,048,576
    unsigned* mx = (unsigned*)(W + 84934656ull);   //   256
    bf16* pfh  = (bf16*)(W + 84934912ull);         //   16,384 proj hi frags
    bf16* pfl  = (bf16*)(W + 84951296ull);         //   16,384 proj lo frags

    hipLaunchKernelGGL(proj_split, dim3(4), dim3(256), 0, stream, proj, pfh, pfl, mx);
    hipLaunchKernelGGL(feat_max, dim3(8192), dim3(64), 0, stream, k, pfh, mx);
    hipLaunchKernelGGL(feat_k, dim3(8192), dim3(64), 0, stream, k, pfh, pfl, mx, kp);
    hipLaunchKernelGGL(chunk_v, dim3(2048), dim3(256), 0, stream, kp, v, S, ds, vbT);
    hipLaunchKernelGGL(prefix_SD, dim3(1024), dim3(256), 0, stream, (unsigned*)S, ds);
    hipLaunchKernelGGL(attn_q, dim3(8192), dim3(64), 0, stream,
                       q, pfh, pfl, kp, vbT, S, ds, out);
}

// Round 9
// 220.784 us; speedup vs baseline: 1.3039x; 1.3039x over previous
//
#include <hip/hip_runtime.h>
#include <math.h>

// Problem constants (match reference)
#define B_ 4
#define L_ 2048
#define H_ 16
#define D_ 64
#define M_ 128
#define TC_ 64              // chunk length
#define NC_ (L_ / TC_)      // 32 chunks
#define EPSK 1e-6f
#define DATA_SCALE 0.35355339059327379f  // 64^{-1/4}
#define RATIO 0.08838834764831845f       // 128^{-1/2}

typedef __bf16 bf16;
typedef bf16 bf16x4 __attribute__((ext_vector_type(4)));
typedef bf16 bf16x8 __attribute__((ext_vector_type(8)));
typedef float floatx4 __attribute__((ext_vector_type(4)));

#define PK64 72     // padded [row][tau] stride (bf16): 144 B rows, 16B-aligned
#define FS_ 136     // feat-tile stride: 272 B rows, 16B-aligned

__device__ __forceinline__ unsigned pk(bf16 a, bf16 b) {
    return (unsigned)__builtin_bit_cast(unsigned short, a) |
           ((unsigned)__builtin_bit_cast(unsigned short, b) << 16);
}

// ---- order-preserving float<->uint for atomic max ----
__device__ __forceinline__ unsigned enc_f(float f) {
    unsigned u = __float_as_uint(f);
    return (u & 0x80000000u) ? ~u : (u | 0x80000000u);
}
__device__ __forceinline__ float dec_f(unsigned u) {
    unsigned b = (u & 0x80000000u) ? (u ^ 0x80000000u) : ~u;
    return __uint_as_float(b);
}

// ---------------------------------------------------------------------------
// One-time: split proj into hi/lo bf16 in MFMA B-fragment order.
// pf[(tc*2 + k0h)*64 + lane][e] = proj[16*tc + (lane&15)][k0h*32 + (lane>>4)*8 + e]
// 16 KB each -> L2-resident for all feat blocks. Also zeroes mx.
// ---------------------------------------------------------------------------
__global__ __launch_bounds__(256) void proj_split(const float* __restrict__ proj,
                                                  bf16* __restrict__ pfh,
                                                  bf16* __restrict__ pfl,
                                                  unsigned* __restrict__ mx) {
    int f = blockIdx.x * 256 + threadIdx.x;   // 0..1023 fragments
    if (blockIdx.x == 0 && threadIdx.x < B_ * H_) mx[threadIdx.x] = 0u;
    int tc = f >> 7, k0h = (f >> 6) & 1, lane = f & 63;
    int lr = lane & 15, quad = lane >> 4;
    const float* src = proj + (16 * tc + lr) * 64 + k0h * 32 + quad * 8;
    float4 x0 = *(const float4*)src;
    float4 x1 = *(const float4*)(src + 4);
    float a[8] = {x0.x, x0.y, x0.z, x0.w, x1.x, x1.y, x1.z, x1.w};
    bf16x8 hi, lo;
#pragma unroll
    for (int e = 0; e < 8; e++) {
        bf16 h = (bf16)a[e];
        hi[e] = h;
        lo[e] = (bf16)(a[e] - (float)h);
    }
    *(bf16x8*)(pfh + (size_t)f * 8) = hi;
    *(bf16x8*)(pfl + (size_t)f * 8) = lo;
}

// ---------------------------------------------------------------------------
// k max pass: dd via hi-only MFMA (16/wave), global per-(b,h) max via atomic.
// ---------------------------------------------------------------------------
__global__ __launch_bounds__(256) void feat_max(const float* __restrict__ k,
                                                const bf16* __restrict__ pfh,
                                                unsigned* __restrict__ mxk) {
    __shared__ float wred[4];
    int tid = threadIdx.x;
    int blk = blockIdx.x;
    int c = blk & 31, h = (blk >> 5) & 15, b = blk >> 9;
    int l0 = c * 64;
    int w = tid >> 6, lane = tid & 63, lr = lane & 15, quad = lane >> 4;

    const float* drow = k +
        ((size_t)(b * L_ + l0 + 16 * w + lr) * H_ + h) * D_ + quad * 8;
    bf16x8 ah[2];
#pragma unroll
    for (int k0 = 0; k0 < 2; k0++) {
        float4 x0 = *(const float4*)(drow + k0 * 32);
        float4 x1 = *(const float4*)(drow + k0 * 32 + 4);
        float a[8] = {x0.x, x0.y, x0.z, x0.w, x1.x, x1.y, x1.z, x1.w};
#pragma unroll
        for (int e = 0; e < 8; e++) ah[k0][e] = (bf16)(DATA_SCALE * a[e]);
    }

    floatx4 acc[8];
#pragma unroll
    for (int tc = 0; tc < 8; tc++) acc[tc] = (floatx4){0.f, 0.f, 0.f, 0.f};
    const bf16x8* ph = (const bf16x8*)pfh + lane;
#pragma unroll
    for (int tc = 0; tc < 8; tc++)
#pragma unroll
        for (int k0 = 0; k0 < 2; k0++) {
            bf16x8 bh = ph[(tc * 2 + k0) * 64];
            acc[tc] = __builtin_amdgcn_mfma_f32_16x16x32_bf16(ah[k0], bh, acc[tc], 0, 0, 0);
        }

    float mm = acc[0][0];
#pragma unroll
    for (int tc = 0; tc < 8; tc++)
#pragma unroll
        for (int reg = 0; reg < 4; reg++) mm = fmaxf(mm, acc[tc][reg]);
#pragma unroll
    for (int off = 1; off < 64; off <<= 1) mm = fmaxf(mm, __shfl_xor(mm, off, 64));
    if (lane == 0) wred[w] = mm;
    __syncthreads();
    if (tid == 0) {
        float g = fmaxf(fmaxf(wred[0], wred[1]), fmaxf(wred[2], wred[3]));
        atomicMax(&mxk[b * H_ + h], enc_f(g));
    }
}

// ---------------------------------------------------------------------------
// k exp pass -> kp in FRAGMENT order per tile: kp[blk*8192 + ((ki*4+tc)*64
// + lane)*8 + e] = kp_val(tau = 16tc + (lane&15), m = 32ki + (lane>>4)*8+e).
// sc slab is wave-local (wave w <-> frags with tc==w) -> NO barrier.
// ---------------------------------------------------------------------------
__global__ __launch_bounds__(256) void feat_k(const float* __restrict__ kin,
                                              const bf16* __restrict__ pfh,
                                              const bf16* __restrict__ pfl,
                                              const unsigned* __restrict__ mxk,
                                              bf16* __restrict__ kp) {
    __shared__ __align__(16) bf16 sc[64 * FS_];
    int tid = threadIdx.x;
    int blk = blockIdx.x;
    int c = blk & 31, h = (blk >> 5) & 15, b = blk >> 9;
    int l0 = c * 64;
    int w = tid >> 6, lane = tid & 63, lr = lane & 15, quad = lane >> 4;

    const float* drow = kin +
        ((size_t)(b * L_ + l0 + 16 * w + lr) * H_ + h) * D_ + quad * 8;
    bf16x8 ah[2], al[2];
    float ss = 0.f;
#pragma unroll
    for (int k0 = 0; k0 < 2; k0++) {
        float4 x0 = *(const float4*)(drow + k0 * 32);
        float4 x1 = *(const float4*)(drow + k0 * 32 + 4);
        float a[8] = {x0.x, x0.y, x0.z, x0.w, x1.x, x1.y, x1.z, x1.w};
#pragma unroll
        for (int e = 0; e < 8; e++) {
            float s = DATA_SCALE * a[e];
            ss += s * s;
            bf16 hh = (bf16)s;
            ah[k0][e] = hh;
            al[k0][e] = (bf16)(s - (float)hh);
        }
    }
    ss += __shfl_xor(ss, 16, 64);
    ss += __shfl_xor(ss, 32, 64);
    float ssrow = 0.5f * ss;

    floatx4 acc[8];
#pragma unroll
    for (int tc = 0; tc < 8; tc++) acc[tc] = (floatx4){0.f, 0.f, 0.f, 0.f};
    const bf16x8* ph = (const bf16x8*)pfh + lane;
    const bf16x8* pl = (const bf16x8*)pfl + lane;
#pragma unroll
    for (int tc = 0; tc < 8; tc++)
#pragma unroll
        for (int k0 = 0; k0 < 2; k0++) {
            bf16x8 bh = ph[(tc * 2 + k0) * 64];
            bf16x8 bl = pl[(tc * 2 + k0) * 64];
            acc[tc] = __builtin_amdgcn_mfma_f32_16x16x32_bf16(ah[k0], bh, acc[tc], 0, 0, 0);
            acc[tc] = __builtin_amdgcn_mfma_f32_16x16x32_bf16(al[k0], bh, acc[tc], 0, 0, 0);
            acc[tc] = __builtin_amdgcn_mfma_f32_16x16x32_bf16(ah[k0], bl, acc[tc], 0, 0, 0);
        }

    int t0 = 16 * w + 4 * quad;
    float mxg = dec_f(mxk[b * H_ + h]);
#pragma unroll
    for (int reg = 0; reg < 4; reg++) {
        float dg = __shfl(ssrow, 4 * quad + reg, 64);
        float sh = dg + mxg;
#pragma unroll
        for (int tc = 0; tc < 8; tc++) {
            float val = RATIO * (__expf(acc[tc][reg] - sh) + EPSK);
            sc[(t0 + reg) * FS_ + 16 * tc + lr] = (bf16)val;   // wave-own rows
        }
    }

    // wave-local frag store: frags (ki*4 + w), straight uint4 LDS->global
    {
        uint4* kout = (uint4*)(kp + (size_t)blk * 8192);
#pragma unroll
        for (int ki = 0; ki < 4; ki++)
            kout[(ki * 4 + w) * 64 + lane] =
                *(const uint4*)(sc + (16 * w + lr) * FS_ + 32 * ki + 8 * quad);
    }
}

// ---------------------------------------------------------------------------
// Chunk sums + V transpose fused. Reads kp (fragment order) and v (fp32),
// builds kT[m][tau] / vT[d][tau] in LDS (lane=tau scalar writes: bank-safe);
// computes S^T[d][m] (stored in fragment order), ds[m]; writes vbT for attn.
// ---------------------------------------------------------------------------
__global__ __launch_bounds__(256) void chunk_v(const bf16* __restrict__ kp,
                                               const float* __restrict__ v,
                                               bf16* __restrict__ S,
                                               float* __restrict__ ds,
                                               bf16* __restrict__ vbT) {
    __shared__ __align__(16) bf16 kT[128 * PK64];   // [m][tau] padded
    __shared__ __align__(16) bf16 vT[64 * PK64];    // [d][tau] padded
    int tid = threadIdx.x;
    int blk = blockIdx.x;
    int c = blk & 31, bh = blk >> 5;
    int h = bh & 15, b = bh >> 4;
    int l0 = c * 64;
    int w = tid >> 6, lane = tid & 63, lr = lane & 15, quad = lane >> 4;

    // kp tile (fragment order) -> kT[m][tau]; lane = tau
    const bf16* kpt = kp + (size_t)blk * 8192;
#pragma unroll
    for (int i = 0; i < 4; i++) {
        int m8 = w * 4 + i;              // 0..15
        bf16x8 kv = *(const bf16x8*)(kpt +
            (((m8 >> 2) * 4 + (lane >> 4)) * 64 + (m8 & 3) * 16 + (lane & 15)) * 8);
#pragma unroll
        for (int e = 0; e < 8; e++) kT[(m8 * 8 + e) * PK64 + lane] = kv[e];
    }
    // v rows (fp32) -> vT[d][tau] bf16; lane = tau
    {
        const float* vrow = v + ((size_t)(b * L_ + l0 + lane) * H_ + h) * D_;
#pragma unroll
        for (int i = 0; i < 4; i++) {
            int d4 = w * 4 + i;          // 0..15
            float4 x = *(const float4*)(vrow + d4 * 4);
            vT[(d4 * 4 + 0) * PK64 + lane] = (bf16)x.x;
            vT[(d4 * 4 + 1) * PK64 + lane] = (bf16)x.y;
            vT[(d4 * 4 + 2) * PK64 + lane] = (bf16)x.z;
            vT[(d4 * 4 + 3) * PK64 + lane] = (bf16)x.w;
        }
    }
    __syncthreads();

    floatx4 acc[8];
#pragma unroll
    for (int tc = 0; tc < 8; tc++) acc[tc] = (floatx4){0.f, 0.f, 0.f, 0.f};
#pragma unroll
    for (int k0 = 0; k0 < 64; k0 += 32) {
        bf16x8 a = *(const bf16x8*)(vT + (16 * w + lr) * PK64 + k0 + quad * 8);
#pragma unroll
        for (int tc = 0; tc < 8; tc++) {
            bf16x8 bb = *(const bf16x8*)(kT + (16 * tc + lr) * PK64 + k0 + quad * 8);
            acc[tc] = __builtin_amdgcn_mfma_f32_16x16x32_bf16(a, bb, acc[tc], 0, 0, 0);
        }
    }

    // vbT [bh][d][L] from vT (pairs contiguous in the transposed tile)
    {
        size_t ob = (size_t)(bh * D_) * (size_t)L_ + l0;
#pragma unroll
        for (int i = 0; i < 8; i++) {
            int e2 = tid + 256 * i;      // 2048 pairs
            int d = e2 >> 5, tau2 = (e2 & 31) * 2;
            *(unsigned*)(vbT + ob + (size_t)d * L_ + tau2) =
                *(const unsigned*)(vT + d * PK64 + tau2);
        }
    }

    // ds[m]: 2 threads per m, 32 taus each (reads kT before repack overwrites)
    float dsv = 0.f;
    {
        int m = tid >> 1, half = tid & 1;
        const bf16x8* kr = (const bf16x8*)(kT + m * PK64 + half * 32);
#pragma unroll
        for (int j = 0; j < 4; j++) {
            bf16x8 vv = kr[j];
#pragma unroll
            for (int e = 0; e < 8; e++) dsv += (float)vv[e];
        }
        dsv += __shfl_xor(dsv, 1, 64);
    }
    __syncthreads();

    // repack acc into kT area in FRAGMENT order (value (d,m) at
    // ((ki*4+tcf)*64 + quadf*16 + lrf)*8 + e), then coalesced flat store
    bf16* scr = kT;
#pragma unroll
    for (int tc = 0; tc < 8; tc++)
#pragma unroll
        for (int reg = 0; reg < 4; reg++)
            scr[((tc >> 1) * 4 + w) * 512 +
                (((((tc & 1) << 1) | (lr >> 3)) * 16) + 4 * quad + reg) * 8 +
                (lr & 7)] = (bf16)acc[tc][reg];
    if ((tid & 1) == 0) ds[(size_t)blk * M_ + (tid >> 1)] = dsv;
    __syncthreads();
#pragma unroll
    for (int i = 0; i < 4; i++) {
        int e = tid + 256 * i;           // 1024 uint4
        ((uint4*)S)[(size_t)blk * 1024 + e] = ((const uint4*)scr)[e];
    }
}

// Exclusive prefix over chunks, bf16 in place (fp32 carries), loads
// prefetched to registers. Positional scan -> layout-agnostic (frag order ok).
// seg==0 blocks also scan ds.
__global__ void prefix_SD(unsigned* __restrict__ S, float* __restrict__ ds) {
    int blk = blockIdx.x;
    int seg = blk & 15, bh = blk >> 4;
    int p = seg * 256 + threadIdx.x;            // 0..4095 uint pairs per chunk
    size_t base = (size_t)bh * NC_ * 4096 + p;
    unsigned uv[NC_];
#pragma unroll
    for (int c = 0; c < NC_; c++) uv[c] = S[base + (size_t)c * 4096];
    float c0 = 0.f, c1 = 0.f;
#pragma unroll
    for (int c = 0; c < NC_; c++) {
        unsigned u = uv[c];
        float f0 = (float)__builtin_bit_cast(bf16, (unsigned short)(u & 0xffffu));
        float f1 = (float)__builtin_bit_cast(bf16, (unsigned short)(u >> 16));
        S[base + (size_t)c * 4096] = pk((bf16)c0, (bf16)c1);
        c0 += f0; c1 += f1;
    }
    if (seg == 0 && threadIdx.x < 128) {
        int m = threadIdx.x;
        size_t dbase = (size_t)bh * NC_ * M_ + m;
        float dv[NC_];
#pragma unroll
        for (int c = 0; c < NC_; c++) dv[c] = ds[dbase + (size_t)c * M_];
        float carry = 0.f;
#pragma unroll
        for (int c = 0; c < NC_; c++) {
            ds[dbase + (size_t)c * M_] = carry;
            carry += dv[c];
        }
    }
}

// ---------------------------------------------------------------------------
// Fused q-feature-map + attention -- BARRIER-FREE (round-7 structure, best
// measured). All LDS (fsc) is wave-local. vT / dprev read DIRECTLY from
// global. Round-9 deltas: (1) kp frag loads+MFMAs guarded by wave-uniform
// tc<=w (-37.5% kp reads, ~6 fewer serial loads/wave; proven in R8);
// (2) den0 hoisted before phase 1 so its dp loads overlap the Sp batch.
// ---------------------------------------------------------------------------
__global__ __launch_bounds__(256, 4) void attn_q(const float* __restrict__ q,
                                                 const bf16* __restrict__ pfh,
                                                 const bf16* __restrict__ pfl,
                                                 const bf16* __restrict__ kp,
                                                 const bf16* __restrict__ vbT,
                                                 const bf16* __restrict__ Sp,
                                                 const float* __restrict__ dp,
                                                 float* __restrict__ out) {
    __shared__ __align__(16) bf16 fsc[64 * FS_];   // [t][m]; scores in cols 0..63

    int tid = threadIdx.x;
    int blk = blockIdx.x;
    int c = blk & 31, bh = blk >> 5;
    int h = bh & 15, b = bh >> 4;
    int l0 = c * 64;
    int w = tid >> 6, lane = tid & 63, lr = lane & 15, quad = lane >> 4;

    // ---- feature map for q tile ----
    const float* drow = q +
        ((size_t)(b * L_ + l0 + 16 * w + lr) * H_ + h) * D_ + quad * 8;
    bf16x8 ah[2], al[2];
    float ss = 0.f;
#pragma unroll
    for (int k0 = 0; k0 < 2; k0++) {
        float4 x0 = *(const float4*)(drow + k0 * 32);
        float4 x1 = *(const float4*)(drow + k0 * 32 + 4);
        float a[8] = {x0.x, x0.y, x0.z, x0.w, x1.x, x1.y, x1.z, x1.w};
#pragma unroll
        for (int e = 0; e < 8; e++) {
            float s = DATA_SCALE * a[e];
            ss += s * s;
            bf16 hh = (bf16)s;
            ah[k0][e] = hh;
            al[k0][e] = (bf16)(s - (float)hh);
        }
    }
    ss += __shfl_xor(ss, 16, 64);
    ss += __shfl_xor(ss, 32, 64);
    float ssrow = 0.5f * ss;

    floatx4 facc[8];
#pragma unroll
    for (int tc = 0; tc < 8; tc++) facc[tc] = (floatx4){0.f, 0.f, 0.f, 0.f};
    {
        const bf16x8* ph = (const bf16x8*)pfh + lane;
        const bf16x8* pl = (const bf16x8*)pfl + lane;
#pragma unroll
        for (int tc = 0; tc < 8; tc++)
#pragma unroll
            for (int k0 = 0; k0 < 2; k0++) {
                bf16x8 bh = ph[(tc * 2 + k0) * 64];
                bf16x8 bl = pl[(tc * 2 + k0) * 64];
                facc[tc] = __builtin_amdgcn_mfma_f32_16x16x32_bf16(ah[k0], bh, facc[tc], 0, 0, 0);
                facc[tc] = __builtin_amdgcn_mfma_f32_16x16x32_bf16(al[k0], bh, facc[tc], 0, 0, 0);
                facc[tc] = __builtin_amdgcn_mfma_f32_16x16x32_bf16(ah[k0], bl, facc[tc], 0, 0, 0);
            }
    }
    int t0 = 16 * w + 4 * quad;
#pragma unroll
    for (int reg = 0; reg < 4; reg++) {
        float m = facc[0][reg];
#pragma unroll
        for (int tc = 1; tc < 8; tc++) m = fmaxf(m, facc[tc][reg]);
        m = fmaxf(m, __shfl_xor(m, 1, 64));
        m = fmaxf(m, __shfl_xor(m, 2, 64));
        m = fmaxf(m, __shfl_xor(m, 4, 64));
        m = fmaxf(m, __shfl_xor(m, 8, 64));
        float dg = __shfl(ssrow, 4 * quad + reg, 64);
        float sh = dg + m;
#pragma unroll
        for (int tc = 0; tc < 8; tc++) {
            float val = RATIO * (__expf(facc[tc][reg] - sh) + EPSK);
            fsc[(t0 + reg) * FS_ + 16 * tc + lr] = (bf16)val;   // wave-own rows
        }
    }

    // Q A-frags from fsc (wave-own rows; in-wave lgkmcnt ordering suffices)
    bf16x8 af[4];
#pragma unroll
    for (int k = 0; k < 4; k++)
        af[k] = *(const bf16x8*)(fsc + (16 * w + lr) * FS_ + 32 * k + quad * 8);

    // den0[16w+lr] = qp_row . dprev (hoisted: independent of Sp/kp; its dp
    // loads issue alongside the Sp batch below)
    float den0v = 0.f;
    {
        const float* dpb = dp + (size_t)blk * M_ + quad * 8;
#pragma unroll
        for (int k = 0; k < 4; k++) {
            float4 d0 = *(const float4*)(dpb + 32 * k);
            float4 d1 = *(const float4*)(dpb + 32 * k + 4);
            den0v += (float)af[k][0] * d0.x + (float)af[k][1] * d0.y +
                     (float)af[k][2] * d0.z + (float)af[k][3] * d0.w +
                     (float)af[k][4] * d1.x + (float)af[k][5] * d1.y +
                     (float)af[k][6] * d1.z + (float)af[k][7] * d1.w;
        }
    }
    den0v += __shfl_xor(den0v, 16, 64);
    den0v += __shfl_xor(den0v, 32, 64);

    floatx4 acc[4];
#pragma unroll
    for (int tc = 0; tc < 4; tc++) acc[tc] = (floatx4){0.f, 0.f, 0.f, 0.f};

    // phase 1: Qp . S_prev (frag-order, contiguous 1KB/wave loads at use)
    {
        const bf16x8* spb = (const bf16x8*)(Sp + (size_t)blk * 8192) + lane;
        bf16x8 sp4[16];
#pragma unroll
        for (int f = 0; f < 16; f++) sp4[f] = spb[f * 64];
#pragma unroll
        for (int ki = 0; ki < 4; ki++)
#pragma unroll
            for (int tc = 0; tc < 4; tc++)
                acc[tc] = __builtin_amdgcn_mfma_f32_16x16x32_bf16(af[ki], sp4[ki * 4 + tc],
                                                                  acc[tc], 0, 0, 0);
    }

    // phase 2a: kp frags tc<=w only (wave-uniform guard; static reg indices)
    floatx4 acc2[4];
#pragma unroll
    for (int tc = 0; tc < 4; tc++) acc2[tc] = (floatx4){0.f, 0.f, 0.f, 0.f};
    {
        const bf16x8* kpb = (const bf16x8*)(kp + (size_t)blk * 8192) + lane;
        bf16x8 kb[16];
#pragma unroll
        for (int ki = 0; ki < 4; ki++)
#pragma unroll
            for (int tc = 0; tc < 4; tc++)
                if (tc <= w) kb[ki * 4 + tc] = kpb[(ki * 4 + tc) * 64];
#pragma unroll
        for (int ki = 0; ki < 4; ki++)
#pragma unroll
            for (int tc = 0; tc < 4; tc++)
                if (tc <= w)
                    acc2[tc] = __builtin_amdgcn_mfma_f32_16x16x32_bf16(af[ki], kb[ki * 4 + tc],
                                                                       acc2[tc], 0, 0, 0);
    }

    // mask + den partials + bf16 scores into wave-own fsc rows (cols 0..63)
    float densc[4];
    {
        float dsum[4] = {0.f, 0.f, 0.f, 0.f};
#pragma unroll
        for (int tc = 0; tc < 4; tc++) {
#pragma unroll
            for (int reg = 0; reg < 4; reg++) {
                int tg = t0 + reg, tau = 16 * tc + lr;
                float vv = (tc <= w) ? acc2[tc][reg] : 0.f;
                if (tau > tg) vv = 0.f;
                dsum[reg] += vv;
                fsc[tg * FS_ + tau] = (bf16)vv;
            }
        }
#pragma unroll
        for (int reg = 0; reg < 4; reg++) {
            float s = dsum[reg];
            s += __shfl_xor(s, 1, 64);
            s += __shfl_xor(s, 2, 64);
            s += __shfl_xor(s, 4, 64);
            s += __shfl_xor(s, 8, 64);
            densc[reg] = s;
        }
    }

    // phase 2b: Sc . V -- scores from wave-own fsc rows, V-frags DIRECT from
    // global vbT (block-exclusive 128B segments; no LDS, no barrier)
    {
        const bf16* vbb = vbT + (size_t)(bh * D_) * L_ + l0 + quad * 8;
        int kmax = (w >= 2) ? 64 : 32;
        for (int k0 = 0; k0 < kmax; k0 += 32) {
            bf16x8 a = *(const bf16x8*)(fsc + (16 * w + lr) * FS_ + k0 + quad * 8);
#pragma unroll
            for (int tc = 0; tc < 4; tc++) {
                bf16x8 bb = *(const bf16x8*)(vbb + (size_t)(16 * tc + lr) * L_ + k0);
                acc[tc] = __builtin_amdgcn_mfma_f32_16x16x32_bf16(a, bb, acc[tc], 0, 0, 0);
            }
        }
    }

    // epilogue
    {
        float inv[4];
#pragma unroll
        for (int reg = 0; reg < 4; reg++) {
            float d0 = __shfl(den0v, 4 * quad + reg, 64);  // row 16w+4q+reg
            inv[reg] = 1.0f / (d0 + densc[reg]);
        }
#pragma unroll
        for (int tc = 0; tc < 4; tc++)
#pragma unroll
            for (int reg = 0; reg < 4; reg++)
                out[((size_t)(b * L_ + l0 + t0 + reg) * H_ + h) * D_ + 16 * tc + lr] =
                    acc[tc][reg] * inv[reg];
    }
}

extern "C" void kernel_launch(void* const* d_in, const int* in_sizes, int n_in,
                              void* d_out, int out_size, void* d_ws, size_t ws_size,
                              hipStream_t stream) {
    const float* q = (const float*)d_in[0];
    const float* k = (const float*)d_in[1];
    const float* v = (const float*)d_in[2];
    const float* proj = (const float*)d_in[3];
    float* out = (float*)d_out;
    char* W = (char*)d_ws;

    // workspace layout (bytes)
    bf16* kp   = (bf16*)(W);                       //  33,554,432  frag-order tiles
    bf16* vbT  = (bf16*)(W + 33554432ull);         //  16,777,216  [bh][d][L]
    bf16* S    = (bf16*)(W + 50331648ull);         //  33,554,432  frag-order tiles
    float* ds  = (float*)(W + 83886080ull);        //   1,048,576
    unsigned* mx = (unsigned*)(W + 84934656ull);   //   256
    bf16* pfh  = (bf16*)(W + 84934912ull);         //   16,384 proj hi frags
    bf16* pfl  = (bf16*)(W + 84951296ull);         //   16,384 proj lo frags

    hipLaunchKernelGGL(proj_split, dim3(4), dim3(256), 0, stream, proj, pfh, pfl, mx);
    hipLaunchKernelGGL(feat_max, dim3(2048), dim3(256), 0, stream, k, pfh, mx);
    hipLaunchKernelGGL(feat_k, dim3(2048), dim3(256), 0, stream, k, pfh, pfl, mx, kp);
    hipLaunchKernelGGL(chunk_v, dim3(2048), dim3(256), 0, stream, kp, v, S, ds, vbT);
    hipLaunchKernelGGL(prefix_SD, dim3(1024), dim3(256), 0, stream, (unsigned*)S, ds);
    hipLaunchKernelGGL(attn_q, dim3(2048), dim3(256), 0, stream,
                       q, pfh, pfl, kp, vbT, S, ds, out);
}